// Round 7
// baseline (461.881 us; speedup 1.0000x reference)
//
#include <hip/hip_runtime.h>
#include <cstdint>
#include <cstddef>

// ---------------- types / helpers ----------------
typedef __attribute__((ext_vector_type(8))) __bf16 bf16x8;
typedef __attribute__((ext_vector_type(16))) float f32x16;

__device__ __forceinline__ unsigned short f2b(float x) {
    uint32_t u = __float_as_uint(x);
    u += 0x7FFFu + ((u >> 16) & 1u);   // RNE
    return (unsigned short)(u >> 16);
}
__device__ __forceinline__ float b2f(unsigned short h) {
    return __uint_as_float(((uint32_t)h) << 16);
}

#define L_SEQ 512
#define N_AA 21
#define NCOL 2688        // 21*128
#define NSEQ 512         // 256 + 256
#define TSTRIDE 448      // padded 441
#define KTOT 10752       // 512*21
#define KWORDS_TOT 336   // 10752/32
#define ZCH 12           // k-chunks for E
#define KCHUNK 896       // 10752/12
#define KWORDS 28        // 896/32
#define KBTOT 672        // 10752/16 k-subtiles

// prep sub-job block ranges
#define PB_WBZ   14112   // 56448/4 fragments
#define PB_EINIT 5376
#define PB_REPACK 1024
#define PB_WBUILD 1024
#define PB_ABITS 672
#define PB_TOTAL (PB_WBZ + PB_EINIT + PB_REPACK + PB_WBUILD + PB_ABITS)

// ---------------- kernel 1: fused prologue (unchanged from R6) ----------------
__global__ __launch_bounds__(256) void prep_kernel(const int* X1, const int* X2,
                                                   const float* W, const float* bvec, const float* wp,
                                                   uint8_t* X8, uint32_t* Abits,
                                                   float* w32, unsigned short* wswz,
                                                   float* E, unsigned short* Wbz) {
    int bid = blockIdx.x;
    int t = threadIdx.x;
    if (bid < PB_WBZ) {
        int f = bid * 4 + (t >> 6);
        int lane = t & 63, lr = lane & 31, hf = lane >> 5;
        int cb = f / KBTOT, kb = f - cb * KBTOT;
        const float* src = W + (size_t)(kb * 16 + hf * 8) * NCOL + cb * 32 + lr;
        union { uint4 q; unsigned short s[8]; } o;
#pragma unroll
        for (int j = 0; j < 8; ++j) o.s[j] = f2b(src[(size_t)j * NCOL]);
        *(uint4*)&Wbz[(size_t)f * 512 + lane * 8] = o.q;
        return;
    }
    bid -= PB_WBZ;
    if (bid < PB_EINIT) {
        int e = bid * 256 + t;
        E[e] = bvec[e % NCOL];
        return;
    }
    bid -= PB_EINIT;
    if (bid < PB_REPACK) {
        int e = bid * 256 + t;
        if (e < 131072) X8[e] = (uint8_t)X1[e];
        else            X8[e] = (uint8_t)X2[e - 131072];
        return;
    }
    bid -= PB_REPACK;
    if (bid < PB_WBUILD) {
        int e = bid * 256 + t;
        int p = e >> 9, q = e & 511;
        float x = 0.0f;
        if (p > q)      x = wp[p * (p - 1) / 2 + q];
        else if (p < q) x = wp[q * (q - 1) / 2 + p];
        float s = 1.0f / (1.0f + expf(-x));
        w32[e] = s;
        int nb = p >> 5, lr = p & 31;
        int kb = q >> 4, hf = (q >> 3) & 1, j = q & 7;
        wswz[(size_t)((nb * 32 + kb) * 512) + (hf * 32 + lr) * 8 + j] = f2b(s);
        return;
    }
    bid -= PB_WBUILD;
    {
        int e = bid * 256 + t;
        if (e >= NSEQ * KWORDS_TOT) return;
        int seq = e / KWORDS_TOT, w = e - seq * KWORDS_TOT;
        int k0 = w * 32;
        int l_lo = k0 / N_AA;
        int l_hi = (k0 + 31) / N_AA;
        if (l_hi > L_SEQ - 1) l_hi = L_SEQ - 1;
        uint32_t bits = 0;
        for (int l = l_lo; l <= l_hi; ++l) {
            int aa = (seq < 256) ? X1[(size_t)seq * L_SEQ + l]
                                 : X2[(size_t)(seq - 256) * L_SEQ + l];
            int pos = l * N_AA + aa - k0;
            if (pos >= 0 && pos < 32) bits |= (1u << pos);
        }
        Abits[e] = bits;
    }
}

// ---------------- kernel 2 core: E-GEMM body (A one-hot from bits, B = Wbz frags) ----
// EPILOGUE==0: atomicAdd into E.  EPILOGUE==1: plain store into Ep[z] partials.
template <int EPILOGUE>
__device__ __forceinline__ void e_mfma_body(const uint32_t* Abits, const unsigned short* Wbz, float* Eout) {
    __shared__ uint32_t Ab[256 * 29];
    int t = threadIdx.x;
    int c0 = blockIdx.x * 128;
    int m0 = blockIdx.y * 256;
    int w0 = blockIdx.z * KWORDS;

    for (int idx = t; idx < 256 * KWORDS; idx += 256) {
        int r = idx / KWORDS, w = idx - r * KWORDS;
        Ab[r * 29 + w] = Abits[(size_t)(m0 + r) * KWORDS_TOT + w0 + w];
    }
    __syncthreads();

    int wid = t >> 6, lane = t & 63;
    int lr = lane & 31, hf = lane >> 5;
    int mbase = (wid & 1) * 128;
    int nbase = (wid >> 1) * 64;

    f32x16 acc[4][2];
#pragma unroll
    for (int s = 0; s < 4; ++s)
#pragma unroll
        for (int o = 0; o < 2; ++o)
#pragma unroll
            for (int r = 0; r < 16; ++r) acc[s][o][r] = 0.f;

    int kb0 = blockIdx.z * (KCHUNK / 16);
    const unsigned short* Bz0 = Wbz + (size_t)(((c0 >> 5) + (wid >> 1) * 2 + 0) * KBTOT + kb0) * 512 + lane * 8;
    const unsigned short* Bz1 = Wbz + (size_t)(((c0 >> 5) + (wid >> 1) * 2 + 1) * KBTOT + kb0) * 512 + lane * 8;

#pragma unroll 2
    for (int ks = 0; ks < KCHUNK / 16; ++ks) {
        int word = ks >> 1;
        int b0 = (ks & 1) * 16 + hf * 8;
        bf16x8 afrag[4];
#pragma unroll
        for (int s = 0; s < 4; ++s) {
            uint32_t bits = Ab[(mbase + s * 32 + lr) * 29 + word];
            uint32_t bb = (bits >> b0) & 0xFFu;
            union { bf16x8 v; uint32_t u[4]; } af;
#pragma unroll
            for (int p = 0; p < 4; ++p) {
                uint32_t u = 0;
                if ((bb >> (2 * p)) & 1u)     u |= 0x3F80u;
                if ((bb >> (2 * p + 1)) & 1u) u |= 0x3F800000u;
                af.u[p] = u;
            }
            afrag[s] = af.v;
        }
        bf16x8 bv0 = *(const bf16x8*)(Bz0 + ks * 512);
        bf16x8 bv1 = *(const bf16x8*)(Bz1 + ks * 512);
#pragma unroll
        for (int s = 0; s < 4; ++s) {
            acc[s][0] = __builtin_amdgcn_mfma_f32_32x32x16_bf16(afrag[s], bv0, acc[s][0], 0, 0, 0);
            acc[s][1] = __builtin_amdgcn_mfma_f32_32x32x16_bf16(afrag[s], bv1, acc[s][1], 0, 0, 0);
        }
    }

#pragma unroll
    for (int s = 0; s < 4; ++s)
#pragma unroll
        for (int o = 0; o < 2; ++o)
#pragma unroll
            for (int r = 0; r < 16; ++r) {
                int row = (r & 3) + 8 * (r >> 2) + 4 * hf;
                int rg = m0 + mbase + s * 32 + row;
                int cg = c0 + nbase + o * 32 + lr;
                if (EPILOGUE == 0) {
                    atomicAdd(Eout + (size_t)rg * NCOL + cg, acc[s][o][r]);
                } else {
                    Eout[((size_t)blockIdx.z * NSEQ + rg) * NCOL + cg] = acc[s][o][r];
                }
            }
}

__global__ __launch_bounds__(256) void e_mfma_bz_at(const uint32_t* Abits, const unsigned short* Wbz, float* E) {
    e_mfma_body<0>(Abits, Wbz, E);
}
__global__ __launch_bounds__(256) void e_mfma_bz_st(const uint32_t* Abits, const unsigned short* Wbz, float* Ep) {
    e_mfma_body<1>(Abits, Wbz, Ep);
}

// ---------------- kernel 3a: T from E (fallback path) ----------------
__global__ __launch_bounds__(256) void t_kernel(const float* E, float* T) {
    __shared__ float4 Es4[21 * 33];
    int t = threadIdx.x, n = blockIdx.x;
    for (int e = t; e < 21 * 32; e += 256) {
        int r = e >> 5, d = e & 31;
        Es4[r * 33 + d] = *(const float4*)(E + (size_t)n * NCOL + r * 128 + d * 4);
    }
    __syncthreads();
    for (int e = t; e < 441; e += 256) {
        int r = e / 21, c = e - r * 21;
        const float4* ar = &Es4[r * 33];
        const float4* br = &Es4[c * 33];
        float s = 0.f;
#pragma unroll 8
        for (int d = 0; d < 32; ++d) {
            float4 a = ar[d], b = br[d];
            s += a.x * b.x + a.y * b.y + a.z * b.z + a.w * b.w;
        }
        T[(size_t)n * TSTRIDE + e] = s;
    }
}

// ---------------- kernel 3b: T from 12 E-partials + bias (no-atomic path) ----------
__global__ __launch_bounds__(256) void t_reduce_kernel(const float* Ep, const float* bvec, float* T) {
    __shared__ float4 Es4[21 * 33];
    int t = threadIdx.x, n = blockIdx.x;
    for (int e = t; e < 21 * 32; e += 256) {
        int r = e >> 5, d = e & 31;
        int c = r * 128 + d * 4;
        float4 s = *(const float4*)&bvec[c];
#pragma unroll
        for (int z = 0; z < ZCH; ++z) {
            float4 v = *(const float4*)&Ep[((size_t)z * NSEQ + n) * NCOL + c];
            s.x += v.x; s.y += v.y; s.z += v.z; s.w += v.w;
        }
        Es4[r * 33 + d] = s;
    }
    __syncthreads();
    for (int e = t; e < 441; e += 256) {
        int r = e / 21, c = e - r * 21;
        const float4* ar = &Es4[r * 33];
        const float4* br = &Es4[c * 33];
        float s = 0.f;
#pragma unroll 8
        for (int d = 0; d < 32; ++d) {
            float4 a = ar[d], b = br[d];
            s += a.x * b.x + a.y * b.y + a.z * b.z + a.w * b.w;
        }
        T[(size_t)n * TSTRIDE + e] = s;
    }
}

// ---------------- kernel 4: kinv, n-tile 4 ----------------
__global__ __launch_bounds__(256) void k_kernel(const uint8_t* X8, const float* T, const float* w32, float* kinv) {
    __shared__ __align__(16) float dvec[4][512];
    __shared__ float Td[4][21];
    __shared__ float red[4][256];
    int t = threadIdx.x, n0 = blockIdx.x * 4;
    if (t < 84) Td[t / 21][t % 21] = T[(size_t)(n0 + t / 21) * TSTRIDE + (t % 21) * 22];
    __syncthreads();
    for (int e = t; e < 2048; e += 256) {
        int nn = e >> 9, l = e & 511;
        dvec[nn][l] = Td[nn][X8[(size_t)(n0 + nn) * 512 + l]];
    }
    __syncthreads();
    float p0 = 0.f, p1 = 0.f, p2 = 0.f, p3 = 0.f;
    for (int p = t; p < 512; p += 256) {
        const float4* wr4 = (const float4*)(w32 + (size_t)p * 512);
        float d0 = 0.f, d1 = 0.f, d2 = 0.f, d3 = 0.f;
        for (int q = 0; q < 128; ++q) {
            float4 wv = wr4[q];
            float4 a = ((const float4*)dvec[0])[q];
            float4 b = ((const float4*)dvec[1])[q];
            float4 c = ((const float4*)dvec[2])[q];
            float4 d = ((const float4*)dvec[3])[q];
            d0 += wv.x * a.x + wv.y * a.y + wv.z * a.z + wv.w * a.w;
            d1 += wv.x * b.x + wv.y * b.y + wv.z * b.z + wv.w * b.w;
            d2 += wv.x * c.x + wv.y * c.y + wv.z * c.z + wv.w * c.w;
            d3 += wv.x * d.x + wv.y * d.y + wv.z * d.z + wv.w * d.w;
        }
        p0 += dvec[0][p] * d0;
        p1 += dvec[1][p] * d1;
        p2 += dvec[2][p] * d2;
        p3 += dvec[3][p] * d3;
    }
    red[0][t] = p0; red[1][t] = p1; red[2][t] = p2; red[3][t] = p3;
    __syncthreads();
    for (int s = 128; s > 0; s >>= 1) {
        if (t < s) {
            red[0][t] += red[0][t + s];
            red[1][t] += red[1][t + s];
            red[2][t] += red[2][t + s];
            red[3][t] += red[3][t + s];
        }
        __syncthreads();
    }
    if (t < 4) kinv[n0 + t] = 1.0f / sqrtf(red[t][0]);
}

// ---------------- kernel 5: S-build (A-fragment-swizzled, one j-half) --------------
// pb = ig*32 + jg: 32 pairs = 8 i's (ig*8..+8) x 4 j's (jh*128 + jg*4..+4),
// pair m = il*4 + jl. Fragment (pb, kt): lane L holds S[m=L&31][p=kt*16+(L>>5)*8+j].
// Fused pre-halved table Tf[m][441] -> ONE gather per element.
__global__ __launch_bounds__(256) void s_build_kernel(const uint8_t* X8, const float* T,
                                                      unsigned short* S, int jh) {
    __shared__ unsigned short Tf[32 * 441];   // 27.6 KB
    __shared__ unsigned short A21[8 * 512];   // 8 KB
    __shared__ uint8_t X2v[4 * 512];          // 2 KB
    int t = threadIdx.x;
    int pb = blockIdx.x;
    int ig = pb >> 5, jg = pb & 31;
    int i0 = ig * 8;
    int j0 = 256 + jh * 128 + jg * 4;   // combined-index rows for X2 side

    for (int e = t; e < 4096; e += 256)
        A21[e] = (unsigned short)(21 * X8[(size_t)i0 * 512 + e]);
    {
        const uint32_t* s2 = (const uint32_t*)(X8 + (size_t)j0 * 512);
        uint32_t* d2 = (uint32_t*)X2v;
        for (int e = t; e < 512; e += 256) d2[e] = s2[e];
    }
    for (int e = t; e < 32 * 441; e += 256) {
        int pr = e / 441, c = e - pr * 441;
        int il = pr >> 2, jl = pr & 3;
        float v = 0.5f * (T[(size_t)(i0 + il) * TSTRIDE + c] + T[(size_t)(j0 + jl) * TSTRIDE + c]);
        Tf[e] = f2b(v);
    }
    __syncthreads();

    int wid = t >> 6, lane = t & 63;
    int m = lane & 31;
    int il = m >> 2, jl = m & 3;
    const unsigned short* tf = &Tf[m * 441];
#pragma unroll
    for (int it = 0; it < 8; ++it) {
        int kt = wid * 8 + it;
        int p0 = kt * 16 + (lane >> 5) * 8;
        union { uint4 q; unsigned short s[8]; } aa;
        aa.q = *(const uint4*)&A21[il * 512 + p0];
        union { uint2 d; uint8_t b[8]; } bb;
        bb.d = *(const uint2*)&X2v[jl * 512 + p0];
        union { uint4 q; unsigned short s[8]; } o;
#pragma unroll
        for (int j = 0; j < 8; ++j) {
            int idx = (int)aa.s[j] + (int)bb.b[j];
            o.s[j] = tf[idx];
        }
        *(uint4*)&S[((size_t)(pb * 32 + kt)) * 512 + lane * 8] = o.q;
    }
}

// ---------------- kernel 6: pair GEMM, zero-LDS K-loop, fused finalize -------------
// Block: 2 pb (64 pairs); wave wid owns n-quarter (4 nb of 32). No barriers in loop.
__global__ __launch_bounds__(256) void k4_gemm_kernel(const unsigned short* S, const unsigned short* wswz,
                                                      const float* kinv, const float* Ainp,
                                                      float* out, int jh) {
    __shared__ float Kred[4][2][32];
    int t = threadIdx.x;
    int wid = t >> 6, lane = t & 63;
    int lr = lane & 31, hf = lane >> 5;
    int pb0 = blockIdx.x * 2;

    const unsigned short* Ab0 = S + (size_t)(pb0 + 0) * 32 * 512 + lane * 8;
    const unsigned short* Ab1 = S + (size_t)(pb0 + 1) * 32 * 512 + lane * 8;

    float prow[2][16];
#pragma unroll
    for (int p = 0; p < 2; ++p)
#pragma unroll
        for (int r = 0; r < 16; ++r) prow[p][r] = 0.f;

#pragma unroll
    for (int nbl = 0; nbl < 4; ++nbl) {
        int nbg = wid * 4 + nbl;
        const unsigned short* Bz = wswz + (size_t)(nbg * 32) * 512 + lane * 8;
        f32x16 acc0, acc1;
#pragma unroll
        for (int r = 0; r < 16; ++r) { acc0[r] = 0.f; acc1[r] = 0.f; }
#pragma unroll 4
        for (int kt = 0; kt < 32; ++kt) {
            bf16x8 av0 = *(const bf16x8*)(Ab0 + kt * 512);
            bf16x8 av1 = *(const bf16x8*)(Ab1 + kt * 512);
            bf16x8 bv  = *(const bf16x8*)(Bz + kt * 512);
            acc0 = __builtin_amdgcn_mfma_f32_32x32x16_bf16(av0, bv, acc0, 0, 0, 0);
            acc1 = __builtin_amdgcn_mfma_f32_32x32x16_bf16(av1, bv, acc1, 0, 0, 0);
        }
        // epilogue: q = nbg*32 + lr; gather S[m][q] from frag layout
        int q = nbg * 32 + lr;
        size_t qoff = (size_t)(q >> 4) * 512 + (size_t)((q & 15) >> 3) * 256 + (q & 7);
        const unsigned short* Sg0 = S + (size_t)(pb0 + 0) * 32 * 512 + qoff;
        const unsigned short* Sg1 = S + (size_t)(pb0 + 1) * 32 * 512 + qoff;
#pragma unroll
        for (int r = 0; r < 16; ++r) {
            int m = (r & 3) + 8 * (r >> 2) + 4 * hf;
            prow[0][r] += acc0[r] * b2f(Sg0[m * 8]);
            prow[1][r] += acc1[r] * b2f(Sg1[m * 8]);
        }
    }

#pragma unroll
    for (int p = 0; p < 2; ++p)
#pragma unroll
        for (int r = 0; r < 16; ++r) {
            float v = prow[p][r];
            v += __shfl_xor(v, 1);
            v += __shfl_xor(v, 2);
            v += __shfl_xor(v, 4);
            v += __shfl_xor(v, 8);
            v += __shfl_xor(v, 16);
            if (lr == 0) {
                int m = (r & 3) + 8 * (r >> 2) + 4 * hf;
                Kred[wid][p][m] = v;
            }
        }
    __syncthreads();

    if (t < 64) {
        int p = t >> 5, m = t & 31;
        float K = Kred[0][p][m] + Kred[1][p][m] + Kred[2][p][m] + Kred[3][p][m];
        int pbg = pb0 + p;
        int ig = pbg >> 5, jg = pbg & 31;
        int i = ig * 8 + (m >> 2);
        int j = jh * 128 + jg * 4 + (m & 3);
        float a0 = Ainp[0];
        out[i * 256 + j] = a0 * a0 * K * kinv[i] * kinv[256 + j];
    }
}

// ---------------- launcher ----------------
extern "C" void kernel_launch(void* const* d_in, const int* in_sizes, int n_in,
                              void* d_out, int out_size, void* d_ws, size_t ws_size,
                              hipStream_t stream) {
    const int*   X1 = (const int*)d_in[0];
    const int*   X2 = (const int*)d_in[1];
    const float* W  = (const float*)d_in[2];
    const float* b  = (const float*)d_in[3];
    const float* wp = (const float*)d_in[4];
    const float* a  = (const float*)d_in[5];
    float* out = (float*)d_out;

    char* ws = (char*)d_ws;
    float*          E     = (float*)(ws + 0);                 // 5,505,024
    float*          T     = (float*)(ws + 5505024);           //   917,504
    float*          w32   = (float*)(ws + 6422528);           // 1,048,576
    unsigned short* wswz  = (unsigned short*)(ws + 7471104);  //   524,288
    float*          kinv  = (float*)(ws + 7995392);           //     2,048
    uint8_t*        X8    = (uint8_t*)(ws + 7997440);         //   262,144
    uint32_t*       Abits = (uint32_t*)(ws + 8259584);        //   688,128  (end 8,947,712)
    unsigned short* Wbz   = (unsigned short*)(ws + 8947712);  // 57,802,752 (end 66,750,464)
    unsigned short* S     = (unsigned short*)(ws + 8947712);  // S overlays Wbz (33,554,432)
    float*          Ep    = (float*)(ws + 66750464);          // 66,060,288 (end 132,810,752)

    const bool ep_path = (ws_size >= (size_t)132810752);

    prep_kernel<<<PB_TOTAL, 256, 0, stream>>>(X1, X2, W, b, wp, X8, Abits, w32, wswz, E, Wbz);
    if (ep_path) {
        e_mfma_bz_st<<<dim3(21, 2, ZCH), 256, 0, stream>>>(Abits, Wbz, Ep);
        t_reduce_kernel<<<512, 256, 0, stream>>>(Ep, b, T);
    } else {
        e_mfma_bz_at<<<dim3(21, 2, ZCH), 256, 0, stream>>>(Abits, Wbz, E);
        t_kernel<<<512, 256, 0, stream>>>(E, T);
    }
    k_kernel<<<128, 256, 0, stream>>>(X8, T, w32, kinv);
    for (int jh = 0; jh < 2; ++jh) {
        s_build_kernel<<<1024, 256, 0, stream>>>(X8, T, S, jh);
        k4_gemm_kernel<<<512, 256, 0, stream>>>(S, wswz, kinv, a, out, jh);
    }
}